// Round 2
// baseline (311.878 us; speedup 1.0000x reference)
//
#include <hip/hip_runtime.h>

// DLRM InteractionArch: B=16384, D=128, F=26, N=27
// out[b] = concat(dense[b] (128 fp32), triu(X X^T, k=1) (351 fp32)),
// X = concat(dense[b][None,:], sparse[b]) : 27 x 128.
//
// One wave per batch element, persistent: 1024 blocks x 256 thr (4 blocks/CU
// by LDS -> all resident, 16 waves/CU), each wave loops 4 elements.
// All synchronization is wave-local (LDS DS pipe is in-order per wave):
// NO __syncthreads anywhere -> no block-wide vmcnt(0) drains, waves
// free-run and overlap loads of iter i+1 with stores of iter i.

#define FEAT 26
#define NROW 27
#define DDIM 128
#define NTRI 351            // 27*26/2
#define OUTW 479            // 128 + 351
#define LDST 136            // LDS row stride in fp16 (16B-aligned rows)
#define WPB   4             // waves per block
#define GRID  1024
#define NWAVE (GRID * WPB)  // 4096 waves
#define ITERS 4             // 4096 * 4 = 16384 batch elements

typedef _Float16 half2v __attribute__((ext_vector_type(2)));
typedef _Float16 half4v __attribute__((ext_vector_type(4)));
typedef _Float16 half8v __attribute__((ext_vector_type(8)));
typedef float    f32x16 __attribute__((ext_vector_type(16)));

// wait lgkmcnt(0) only (vmcnt/expcnt unconstrained): 0xC07F
#define LGKM0() __builtin_amdgcn_s_waitcnt(0xC07F)

__global__ __launch_bounds__(256) void interaction_kernel(
    const float* __restrict__ dense,
    const float* __restrict__ sparse,
    float* __restrict__ out)
{
    __shared__ _Float16 Xs[WPB][32][LDST];   // per-wave 27x128 fp16 tile
    __shared__ float    Tri[WPB][NTRI + 1];  // per-wave triangle staging

    const int lane = threadIdx.x & 63;
    const int w    = threadIdx.x >> 6;
    const int gw   = blockIdx.x * WPB + w;   // 0..4095

    const int j0 = lane & 31;                // C/D column held by this lane
    const int q  = lane >> 5;
    const half8v* fp = (const half8v*)(&Xs[w][j0][q * 8]);

    for (int it = 0; it < ITERS; ++it) {
        const long b = gw + (long)it * NWAVE;
        const float* dn   = dense  + b * DDIM;
        const float* sp   = sparse + b * (FEAT * DDIM);
        float*       orow = out    + b * OUTW;

        // ---- dense row: fp32 straight to out, fp16 to LDS row 0
        {
            float2 v = *(const float2*)(dn + lane * 2);
            orow[lane * 2 + 0] = v.x;
            orow[lane * 2 + 1] = v.y;
            half2v h;
            h.x = (_Float16)v.x; h.y = (_Float16)v.y;
            *(half2v*)(&Xs[w][0][lane * 2]) = h;
        }

        // ---- sparse rows 1..26: 832 float4, 13 iters x 64 lanes
#pragma unroll
        for (int t = 0; t < 13; ++t) {
            int idx = t * 64 + lane;           // 0..831
            float4 v = *(const float4*)(sp + idx * 4);
            int row = 1 + (idx >> 5);          // 1..26
            int col = (idx & 31) * 4;          // 0..124
            half4v h;
            h.x = (_Float16)v.x; h.y = (_Float16)v.y;
            h.z = (_Float16)v.z; h.w = (_Float16)v.w;
            *(half4v*)(&Xs[w][row][col]) = h;  // 8B, 2-way bank alias (free)
        }
        __builtin_amdgcn_wave_barrier();       // no code motion across
        LGKM0();                               // all ds_writes landed (wave-local)

        // ---- Gram via MFMA: same fragment as A and B -> C = X X^T.
        f32x16 acc = {0,0,0,0,0,0,0,0,0,0,0,0,0,0,0,0};
#pragma unroll
        for (int s = 0; s < 8; ++s) {
            half8v f = fp[2 * s];              // 16 halfs (32B) per K-step
            acc = __builtin_amdgcn_mfma_f32_32x32x16_f16(f, f, acc, 0, 0, 0);
        }

        // ---- extract triu(k=1): C/D layout col=lane&31, row=(reg&3)+8*(reg>>2)+4*q
#pragma unroll
        for (int reg = 0; reg < 16; ++reg) {
            int row = (reg & 3) + 8 * (reg >> 2) + 4 * q;
            if (row < j0 && j0 < NROW) {
                int t = row * (2 * NROW - row - 1) / 2 + (j0 - row - 1);
                Tri[w][t] = acc[reg];
            }
        }
        __builtin_amdgcn_wave_barrier();
        LGKM0();                               // Tri writes landed (wave-local)

        // ---- coalesced triangle store
#pragma unroll
        for (int t = 0; t < 6; ++t) {
            int idx = t * 64 + lane;
            if (idx < NTRI) orow[DDIM + idx] = Tri[w][idx];
        }
        __builtin_amdgcn_wave_barrier();       // keep next iter's ds_writes behind Tri reads
    }
}

extern "C" void kernel_launch(void* const* d_in, const int* in_sizes, int n_in,
                              void* d_out, int out_size, void* d_ws, size_t ws_size,
                              hipStream_t stream) {
    const float* dense  = (const float*)d_in[0];
    const float* sparse = (const float*)d_in[1];
    float* out = (float*)d_out;
    interaction_kernel<<<GRID, 256, 0, stream>>>(dense, sparse, out);
}

// Round 3
// 310.401 us; speedup vs baseline: 1.0048x; 1.0048x over previous
//
#include <hip/hip_runtime.h>

// DLRM InteractionArch: B=16384, D=128, F=26, N=27
// out[b] = concat(dense[b] (128 fp32), triu(X X^T, k=1) (351 fp32)),
// X = concat(dense[b][None,:], sparse[b]) : 27 x 128.
//
// One wave per batch element, persistent (2048 blocks x 4 waves x 2 iters).
// MFMA fragments are loaded DIRECTLY from global memory in A-operand layout
// (lane l <- X[l&31][s*16 + (l>>5)*8 ..+7], two aligned float4 per s; lane
// pairs (l,l+32) cover one 64B line per row -> fully coalesced, zero LDS
// staging for X). Rows 27..31 clamp to row 26 (same cachelines, outputs
// never extracted). Only the 351-element triangle goes through LDS for
// coalesced stores. All sync is wave-local: no __syncthreads anywhere.

#define FEAT 26
#define NROW 27
#define DDIM 128
#define NTRI 351            // 27*26/2
#define OUTW 479            // 128 + 351
#define WPB   4
#define GRID  2048
#define NWAVE (GRID * WPB)  // 8192
#define ITERS 2             // 8192 * 2 = 16384

typedef _Float16 half8v __attribute__((ext_vector_type(8)));
typedef float    f32x16 __attribute__((ext_vector_type(16)));

// wait lgkmcnt(0) only (vmcnt/expcnt unconstrained): 0xC07F
#define LGKM0() __builtin_amdgcn_s_waitcnt(0xC07F)

__global__ __launch_bounds__(256) void interaction_kernel(
    const float* __restrict__ dense,
    const float* __restrict__ sparse,
    float* __restrict__ out)
{
    __shared__ float Tri[WPB][NTRI + 1];     // per-wave triangle staging only

    const int lane = threadIdx.x & 63;
    const int w    = threadIdx.x >> 6;
    const int gw   = blockIdx.x * WPB + w;   // 0..8191

    const int r  = lane & 31;                // fragment row / C-column j0
    const int q  = lane >> 5;
    const int rr = (r > FEAT) ? FEAT : r;    // clamp rows 27..31 -> 26

    for (int it = 0; it < ITERS; ++it) {
        const long b = gw + (long)it * NWAVE;
        const float* dn   = dense  + b * DDIM;
        const float* sp   = sparse + b * (FEAT * DDIM);
        float*       orow = out    + b * OUTW;

        // per-lane fragment row base: row 0 = dense, rows 1..26 = sparse
        const float* rowp = (rr == 0) ? dn : (sp + (rr - 1) * DDIM);

        // ---- load A-fragment straight from global, convert to fp16
        half8v fr[8];
#pragma unroll
        for (int s = 0; s < 8; ++s) {
            const float* p = rowp + s * 16 + q * 8;
            float4 a = *(const float4*)(p);
            float4 c = *(const float4*)(p + 4);
            half8v f;
            f[0] = (_Float16)a.x; f[1] = (_Float16)a.y;
            f[2] = (_Float16)a.z; f[3] = (_Float16)a.w;
            f[4] = (_Float16)c.x; f[5] = (_Float16)c.y;
            f[6] = (_Float16)c.z; f[7] = (_Float16)c.w;
            fr[s] = f;
        }

        // ---- dense row fp32 passthrough to out (same lines as row-0 frags)
        {
            float2 v = *(const float2*)(dn + lane * 2);
            orow[lane * 2 + 0] = v.x;
            orow[lane * 2 + 1] = v.y;
        }

        // ---- Gram: same fragment as A and B -> C = X X^T
        f32x16 acc = {0,0,0,0,0,0,0,0,0,0,0,0,0,0,0,0};
#pragma unroll
        for (int s = 0; s < 8; ++s)
            acc = __builtin_amdgcn_mfma_f32_32x32x16_f16(fr[s], fr[s], acc, 0, 0, 0);

        // ---- extract triu(k=1): C/D layout col=lane&31, row=(reg&3)+8*(reg>>2)+4*q
#pragma unroll
        for (int reg = 0; reg < 16; ++reg) {
            int row = (reg & 3) + 8 * (reg >> 2) + 4 * q;
            if (row < r && r < NROW) {
                int t = row * (2 * NROW - row - 1) / 2 + (r - row - 1);
                Tri[w][t] = acc[reg];
            }
        }
        LGKM0();                              // wave-local: own ds_writes landed

        // ---- coalesced triangle store
#pragma unroll
        for (int t = 0; t < 6; ++t) {
            int idx = t * 64 + lane;
            if (idx < NTRI) orow[DDIM + idx] = Tri[w][idx];
        }
        __builtin_amdgcn_wave_barrier();      // next iter's Tri writes stay behind these reads
    }
}

extern "C" void kernel_launch(void* const* d_in, const int* in_sizes, int n_in,
                              void* d_out, int out_size, void* d_ws, size_t ws_size,
                              hipStream_t stream) {
    const float* dense  = (const float*)d_in[0];
    const float* sparse = (const float*)d_in[1];
    float* out = (float*)d_out;
    interaction_kernel<<<GRID, 256, 0, stream>>>(dense, sparse, out);
}